// Round 1
// baseline (289.957 us; speedup 1.0000x reference)
//
#include <hip/hip_runtime.h>

// Problem constants (fixed by setup_inputs in the reference)
#define T_TABLES  8
#define N_TAB     2097152          // indices per table (2^21)
#define B_TAB     8192             // batch per table (2^13); offsets len = B_TAB+1
#define NV_TAB    (N_TAB / 4)      // 524288 = 2^19 vec4 chunks per table
#define LOG2_NV   19
#define LOG2_NTAB 21
#define LOG2_B    13

#define TOTAL_IDX (T_TABLES * N_TAB)       // 16777216
#define N_OFF_OUT (T_TABLES * B_TAB + 1)   // 65537
#define NVEC      (T_TABLES * NV_TAB)      // 4194304 vec4 chunks (idx region)
#define NTHREADS  2097152                  // 8192 blocks x 256 threads
#define NCHUNK_W  (2 * NTHREADS - 1)       // 4194303 dest-ALIGNED weight chunks

struct TablePtrs {
    const int*   idx[T_TABLES];
    const int*   off[T_TABLES];
    const float* wgt[T_TABLES];
};

// 4B-aligned float4: used only for the (now) misaligned weights-region LOADS.
// Weights OUT region starts at float index 16842753 (byte % 16 == 4), so we
// tile region 2 on destination-aligned chunks g = 3 + 4c; the 4B straddle
// moves to the read path, stores are all 16B-aligned.
typedef float __attribute__((ext_vector_type(4), aligned(4))) float4u;
typedef float __attribute__((ext_vector_type(4)))             float4v;
typedef int   __attribute__((ext_vector_type(4)))             int4v;

__global__ __launch_bounds__(256)
void tbe_prep_kernel(TablePtrs p, float* __restrict__ out) {
    float* __restrict__ out_idx = out;                         // [0, 16777216)
    float* __restrict__ out_off = out + TOTAL_IDX;             // [.., +65537)
    float* __restrict__ out_w   = out + TOTAL_IDX + N_OFF_OUT; // [.., +16777216)

    const int tid = blockIdx.x * blockDim.x + threadIdx.x;

    // ---- Region 1: indices -> f32. Both sides 16B-aligned; 2 chunks/thread.
    // Regular (cached) loads: inputs were just rewritten by the harness
    // restore, so lines are plausibly L2/LLC-resident; don't mark evict-first.
    const int v0 = tid;
    const int v1 = tid + NTHREADS;   // NVEC == 2*NTHREADS, no bounds check
    const int t0 = v0 >> LOG2_NV, j0 = (v0 & (NV_TAB - 1)) << 2;
    const int t1 = v1 >> LOG2_NV, j1 = (v1 & (NV_TAB - 1)) << 2;
    const int4v ia = *(const int4v*)(p.idx[t0] + j0);
    const int4v ib = *(const int4v*)(p.idx[t1] + j1);

    // ---- Region 2 (weights): destination-aligned chunks g = 3 + 4c.
    // c0 always valid; c1 valid except for the single last thread.
    const int  c0   = tid;
    const int  c1   = tid + NTHREADS;
    const bool has1 = (c1 < NCHUNK_W);
    const int  g0   = (c0 << 2) + 3;
    const int  g1   = (c1 << 2) + 3;
    const int  tw0 = g0 >> LOG2_NTAB, jw0 = g0 & (N_TAB - 1);
    const int  tw1 = g1 >> LOG2_NTAB, jw1 = g1 & (N_TAB - 1);

    // Misaligned-by-4B 16B loads; 7 chunks sit on a table boundary
    // (jw == N_TAB-1) and must gather 1+3 floats from adjacent tables
    // (a plain 16B load there would read OOB past that table's buffer).
    float4v wa, wb;
    if (jw0 != N_TAB - 1) {
        wa = (float4v)(*(const float4u*)(p.wgt[tw0] + jw0));
    } else {
        wa[0] = p.wgt[tw0][N_TAB - 1];
        wa[1] = p.wgt[tw0 + 1][0];
        wa[2] = p.wgt[tw0 + 1][1];
        wa[3] = p.wgt[tw0 + 1][2];
    }
    if (has1) {
        if (jw1 != N_TAB - 1) {
            wb = (float4v)(*(const float4u*)(p.wgt[tw1] + jw1));
        } else {
            wb[0] = p.wgt[tw1][N_TAB - 1];
            wb[1] = p.wgt[tw1 + 1][0];
            wb[2] = p.wgt[tw1 + 1][1];
            wb[3] = p.wgt[tw1 + 1][2];
        }
    }

    // int -> f32 (exact: vocab < 2^24)
    float4v oa, ob;
    oa[0] = (float)ia[0]; oa[1] = (float)ia[1]; oa[2] = (float)ia[2]; oa[3] = (float)ia[3];
    ob[0] = (float)ib[0]; ob[1] = (float)ib[1]; ob[2] = (float)ib[2]; ob[3] = (float)ib[3];

    // All stores 16B-aligned, streaming (write-once).
    __builtin_nontemporal_store(oa, (float4v*)(out_idx + (v0 << 2)));
    __builtin_nontemporal_store(ob, (float4v*)(out_idx + (v1 << 2)));
    __builtin_nontemporal_store(wa, (float4v*)(out_w + g0));
    if (has1)
        __builtin_nontemporal_store(wb, (float4v*)(out_w + g1));

    // Weights region head (3 floats) + tail (1 float) not covered by chunks.
    if (tid == 0) {
        out_w[0] = p.wgt[0][0];
        out_w[1] = p.wgt[0][1];
        out_w[2] = p.wgt[0][2];
        out_w[TOTAL_IDX - 1] = p.wgt[T_TABLES - 1][N_TAB - 1];
    }

    // ---- Region 3: rebased offsets (65537 scalar f32 stores; exact, max 2^24)
    if (tid < T_TABLES * B_TAB) {
        const int t = tid >> LOG2_B;
        const int k = tid & (B_TAB - 1);
        out_off[tid] = (float)(p.off[t][k] + t * N_TAB);
    } else if (tid == T_TABLES * B_TAB) {
        out_off[tid] = (float)TOTAL_IDX;   // grand total = 16777216 (exact in f32)
    }
}

extern "C" void kernel_launch(void* const* d_in, const int* in_sizes, int n_in,
                              void* d_out, int out_size, void* d_ws, size_t ws_size,
                              hipStream_t stream) {
    // setup_inputs() builds its dict INSIDE the per-table loop, so d_in is
    // interleaved triplets: [indices_0, offsets_0, weights_0, indices_1, ...].
    // Detect layout defensively via in_sizes (offsets are the only 8193-sized
    // inputs): interleaved -> in_sizes[1]==8193; grouped -> in_sizes[8]==8193.
    TablePtrs p;
    const bool interleaved = (n_in >= 2 && in_sizes[1] == B_TAB + 1);
    for (int i = 0; i < T_TABLES; ++i) {
        if (interleaved) {
            p.idx[i] = (const int*)  d_in[3 * i + 0];
            p.off[i] = (const int*)  d_in[3 * i + 1];
            p.wgt[i] = (const float*)d_in[3 * i + 2];
        } else {
            p.idx[i] = (const int*)  d_in[i];
            p.off[i] = (const int*)  d_in[T_TABLES + i];
            p.wgt[i] = (const float*)d_in[2 * T_TABLES + i];
        }
    }
    float* out = (float*)d_out;

    // 8192 blocks x 256 threads = 2M threads: 2 vec4 chunks per thread per
    // region, fully unrolled in-kernel. Pure-BW kernel; heavy oversubscription.
    dim3 grid(8192), block(256);
    hipLaunchKernelGGL(tbe_prep_kernel, grid, block, 0, stream, p, out);
}

// Round 2
// 260.650 us; speedup vs baseline: 1.1124x; 1.1124x over previous
//
#include <hip/hip_runtime.h>

// Problem constants (fixed by setup_inputs in the reference)
#define T_TABLES  8
#define N_TAB     2097152          // indices per table (2^21)
#define B_TAB     8192             // batch per table (2^13); offsets len = B_TAB+1
#define NV_TAB    (N_TAB / 4)      // 524288 = 2^19 vec4 chunks per table
#define LOG2_NV   19
#define LOG2_NTAB 21
#define LOG2_B    13

#define TOTAL_IDX (T_TABLES * N_TAB)       // 16777216
#define N_OFF_OUT (T_TABLES * B_TAB + 1)   // 65537
#define NTHREADS  2097152                  // 8192 blocks x 256 threads
#define WPB       2048                     // weight floats per block (2048 | 2^21
                                           // -> every block's range is in ONE table)

struct TablePtrs {
    const int*   idx[T_TABLES];
    const int*   off[T_TABLES];
    const float* wgt[T_TABLES];
};

typedef float __attribute__((ext_vector_type(4))) float4v;
typedef int   __attribute__((ext_vector_type(4))) int4v;

__global__ __launch_bounds__(256)
void tbe_prep_kernel(TablePtrs p, float* __restrict__ out) {
    // 8 KiB staging buffer for the weights realignment (region 2).
    __shared__ float lds[WPB];

    float* __restrict__ out_idx = out;                         // [0, 16777216)
    float* __restrict__ out_off = out + TOTAL_IDX;             // [.., +65537)
    float* __restrict__ out_w   = out + TOTAL_IDX + N_OFF_OUT; // [.., +16777216)
    // out_w begins at float index 16842753 (byte % 16 == 4): dest-aligned 16B
    // chunks within a block's 2048-float window start at local offset 3 + 4c.

    const int tid = blockIdx.x * blockDim.x + threadIdx.x;
    const int i   = threadIdx.x;

    // ---- Issue ALL global loads unconditionally up-front (deep VMEM queue).
    // Region 1 (indices): both sides 16B-aligned, 2 chunks/thread.
    const int v0 = tid;
    const int v1 = tid + NTHREADS;
    const int t0 = v0 >> LOG2_NV, j0 = (v0 & (NV_TAB - 1)) << 2;
    const int t1 = v1 >> LOG2_NV, j1 = (v1 & (NV_TAB - 1)) << 2;
    const int4v ia = __builtin_nontemporal_load((const int4v*)(p.idx[t0] + j0));
    const int4v ib = __builtin_nontemporal_load((const int4v*)(p.idx[t1] + j1));

    // Region 2 (weights): block-local window [D0, D0+2048), source-ALIGNED loads.
    const int    D0   = blockIdx.x * WPB;
    const int    tw   = D0 >> LOG2_NTAB;        // whole block in one table
    const int    jw   = D0 & (N_TAB - 1);
    const float* wsrc = p.wgt[tw] + jw;
    const float4v wa = __builtin_nontemporal_load((const float4v*)(wsrc + 4 * i));
    const float4v wb = __builtin_nontemporal_load((const float4v*)(wsrc + 4 * (i + 256)));

    // Stage weights into LDS (contiguous b128 writes, conflict-free).
    *(float4v*)(lds + 4 * i)         = wa;
    *(float4v*)(lds + 4 * (i + 256)) = wb;

    // Region 1: int -> f32 (exact, vocab < 2^24), aligned streaming stores.
    float4v oa, ob;
    oa[0] = (float)ia[0]; oa[1] = (float)ia[1]; oa[2] = (float)ia[2]; oa[3] = (float)ia[3];
    ob[0] = (float)ib[0]; ob[1] = (float)ib[1]; ob[2] = (float)ib[2]; ob[3] = (float)ib[3];
    __builtin_nontemporal_store(oa, (float4v*)(out_idx + (v0 << 2)));
    __builtin_nontemporal_store(ob, (float4v*)(out_idx + (v1 << 2)));

    // Region 3: rebased offsets (65537 scalar f32 stores; exact, max 2^24).
    if (tid < T_TABLES * B_TAB) {
        const int t = tid >> LOG2_B;
        const int k = tid & (B_TAB - 1);
        out_off[tid] = (float)(p.off[t][k] + t * N_TAB);
    } else if (tid == T_TABLES * B_TAB) {
        out_off[tid] = (float)TOTAL_IDX;   // grand total = 16777216 (exact in f32)
    }

    __syncthreads();

    // Region 2 stores: read LDS shifted by +3 floats (8-way bank conflict on an
    // otherwise-idle LDS pipe), store dest-ALIGNED 16B chunks. 511 chunks cover
    // [D0+3, D0+2047); head 3 + tail 1 floats via scalar aligned dword stores.
    float* __restrict__ wdst = out_w + D0;
    {
        const int c = i;                                  // c in [0, 256)
        float4v s;
        s[0] = lds[3 + 4 * c]; s[1] = lds[4 + 4 * c];
        s[2] = lds[5 + 4 * c]; s[3] = lds[6 + 4 * c];
        __builtin_nontemporal_store(s, (float4v*)(wdst + 3 + 4 * c));
    }
    if (i < 255) {
        const int c = i + 256;                            // c in [256, 511)
        float4v s;
        s[0] = lds[3 + 4 * c]; s[1] = lds[4 + 4 * c];
        s[2] = lds[5 + 4 * c]; s[3] = lds[6 + 4 * c];
        __builtin_nontemporal_store(s, (float4v*)(wdst + 3 + 4 * c));
    } else {
        // i == 255: head (3 floats) + tail (1 float) of this block's window.
        wdst[0]       = lds[0];
        wdst[1]       = lds[1];
        wdst[2]       = lds[2];
        wdst[WPB - 1] = lds[WPB - 1];
    }
}

extern "C" void kernel_launch(void* const* d_in, const int* in_sizes, int n_in,
                              void* d_out, int out_size, void* d_ws, size_t ws_size,
                              hipStream_t stream) {
    // setup_inputs() builds its dict INSIDE the per-table loop, so d_in is
    // interleaved triplets: [indices_0, offsets_0, weights_0, indices_1, ...].
    // Detect layout defensively via in_sizes (offsets are the only 8193-sized
    // inputs): interleaved -> in_sizes[1]==8193; grouped -> in_sizes[8]==8193.
    TablePtrs p;
    const bool interleaved = (n_in >= 2 && in_sizes[1] == B_TAB + 1);
    for (int i = 0; i < T_TABLES; ++i) {
        if (interleaved) {
            p.idx[i] = (const int*)  d_in[3 * i + 0];
            p.off[i] = (const int*)  d_in[3 * i + 1];
            p.wgt[i] = (const float*)d_in[3 * i + 2];
        } else {
            p.idx[i] = (const int*)  d_in[i];
            p.off[i] = (const int*)  d_in[T_TABLES + i];
            p.wgt[i] = (const float*)d_in[2 * T_TABLES + i];
        }
    }
    float* out = (float*)d_out;

    // 8192 blocks x 256 threads: 2 idx chunks + 2 weight chunks per thread,
    // fully unrolled in-kernel. Pure-BW kernel; heavy oversubscription.
    dim3 grid(8192), block(256);
    hipLaunchKernelGGL(tbe_prep_kernel, grid, block, 0, stream, p, out);
}